// Round 1
// baseline (990.373 us; speedup 1.0000x reference)
//
#include <hip/hip_runtime.h>
#include <hip/hip_bf16.h>

typedef __bf16 bf16_t;
typedef __bf16 bf16x8 __attribute__((ext_vector_type(8)));
typedef float f32x16 __attribute__((ext_vector_type(16)));

#define EPS 0.5f
#define OLDW 1032   // o LDS row stride (1024 used + 8 pad to break bank stride)
#define HLDW 136    // h LDS row stride (128 used + 8 pad)

// ---------------- one-time weight conversion ----------------
// W1 [1024][128] f32 -> W1t [128][1024] bf16  (W1t[j][i] = W1[i][j])
// W2 [128][1000] f32 -> W2b [128][1024] bf16  (k-padded zeros)
//                    -> W2t [1024][128] bf16  (W2t[k][j] = W2[j][k], row-padded zeros)
__global__ __launch_bounds__(256) void prep_weights(
    const float* __restrict__ W1, const float* __restrict__ W2,
    bf16_t* __restrict__ W1t, bf16_t* __restrict__ W2b, bf16_t* __restrict__ W2t) {
  int idx = blockIdx.x * 256 + threadIdx.x;
  if (idx < 131072) {
    { int j = idx >> 10, i = idx & 1023; W1t[idx] = (bf16_t)W1[i * 128 + j]; }
    { int j = idx >> 10, k = idx & 1023;
      W2b[idx] = (bf16_t)((k < 1000) ? W2[j * 1000 + k] : 0.f); }
    { int k = idx >> 7, j = idx & 127;
      W2t[idx] = (bf16_t)((k < 1000) ? W2[j * 1000 + k] : 0.f); }
  }
}

// ---------------- A = x @ W1 (f32 out), bf16 MFMA ----------------
__global__ __launch_bounds__(256) void gemm_A(
    const float* __restrict__ x, const bf16_t* __restrict__ W1t,
    float* __restrict__ A) {
  int lane = threadIdx.x & 63, w = threadIdx.x >> 6;
  int row0 = blockIdx.x * 64;
  int mt = w & 1, np = (w >> 1) * 2;  // m-tile, first n-tile of pair
  f32x16 acc0 = {}, acc1 = {};
  int ar = row0 + mt * 32 + (lane & 31);
  int kg = (lane >> 5) * 8;
  const float* xrow = x + (size_t)ar * 1024 + kg;
  const bf16_t* b0 = W1t + ((np * 32 + (lane & 31)) << 10) + kg;
  const bf16_t* b1 = W1t + (((np + 1) * 32 + (lane & 31)) << 10) + kg;
#pragma unroll 4
  for (int ks = 0; ks < 64; ++ks) {
    float xv[8];
    *(float4*)&xv[0] = *(const float4*)(xrow + ks * 16);
    *(float4*)&xv[4] = *(const float4*)(xrow + ks * 16 + 4);
    bf16x8 a;
#pragma unroll
    for (int i = 0; i < 8; ++i) a[i] = (bf16_t)xv[i];
    bf16x8 f0 = *(const bf16x8*)(b0 + ks * 16);
    bf16x8 f1 = *(const bf16x8*)(b1 + ks * 16);
    acc0 = __builtin_amdgcn_mfma_f32_32x32x16_bf16(a, f0, acc0, 0, 0, 0);
    acc1 = __builtin_amdgcn_mfma_f32_32x32x16_bf16(a, f1, acc1, 0, 0, 0);
  }
#pragma unroll
  for (int reg = 0; reg < 16; ++reg) {
    int r = mt * 32 + (reg & 3) + 8 * (reg >> 2) + 4 * (lane >> 5);
    A[(size_t)(row0 + r) * 128 + np * 32 + (lane & 31)] = acc0[reg];
    A[(size_t)(row0 + r) * 128 + (np + 1) * 32 + (lane & 31)] = acc1[reg];
  }
}

// ---------------- persistent relaxation + log_softmax ----------------
__global__ __launch_bounds__(512) void eqprop(
    const float* __restrict__ h0, const float* __restrict__ o0,
    const float* __restrict__ b_h, const float* __restrict__ b_o,
    const float* __restrict__ A, const bf16_t* __restrict__ W2b,
    const bf16_t* __restrict__ W2t, const int* __restrict__ nit,
    float* __restrict__ out) {
  __shared__ bf16_t o_lds[64 * OLDW];  // 132096 B
  __shared__ bf16_t h_lds[64 * HLDW];  //  17408 B
  int tid = threadIdx.x, lane = tid & 63, w = tid >> 6;
  int row0 = blockIdx.x * 64;

  // init state from inputs (zeros, but be faithful); pad regions = 0
  for (int idx = tid; idx < 64 * OLDW; idx += 512) {
    int r = idx / OLDW, k = idx - r * OLDW;
    float v = (k < 1000) ? o0[(size_t)(row0 + r) * 1000 + k] : 0.f;
    o_lds[idx] = (bf16_t)v;
  }
  for (int idx = tid; idx < 64 * HLDW; idx += 512) {
    int r = idx / HLDW, j = idx - r * HLDW;
    float v = (j < 128) ? h0[(size_t)(row0 + r) * 128 + j] : 0.f;
    h_lds[idx] = (bf16_t)v;
  }
  int T = nit[0];
  int mw = w >> 2, nw = w & 3;          // C-pass wave grid: 2m x 4n
  int arow = mw * 32 + (lane & 31);
  int kg = (lane >> 5) * 8;

  for (int t = 0; t < T; ++t) {
    __syncthreads();  // state writes of prev iter (and init) visible
    // ---- C-pass: C[b,j] = sum_k o[b,k] * W2[j,k], one 32x32 tile per wave
    f32x16 accc = {};
    {
      const bf16_t* bp = W2b + ((nw * 32 + (lane & 31)) << 10) + kg;
      const bf16_t* ap = o_lds + arow * OLDW + kg;
#pragma unroll 4
      for (int ks = 0; ks < 64; ++ks) {
        bf16x8 a = *(const bf16x8*)(ap + ks * 16);
        bf16x8 b = *(const bf16x8*)(bp + ks * 16);
        accc = __builtin_amdgcn_mfma_f32_32x32x16_bf16(a, b, accc, 0, 0, 0);
      }
    }
    __syncthreads();  // all waves done reading o_t before o is overwritten

    // ---- D-pass: D[b,k] = sum_j h[b,j]*W2[j,k]; fused o-update in place
    bf16x8 hf[2][8];  // h_t as A-fragments, preloaded (64 VGPR)
#pragma unroll
    for (int mt = 0; mt < 2; ++mt)
#pragma unroll
      for (int kk = 0; kk < 8; ++kk)
        hf[mt][kk] = *(const bf16x8*)(h_lds + (mt * 32 + (lane & 31)) * HLDW + kk * 16 + kg);

    for (int nt = w * 4; nt < w * 4 + 4; ++nt) {  // each wave: 4 n-tiles
      f32x16 acc0 = {}, acc1 = {};
      const bf16_t* wt = W2t + ((nt * 32 + (lane & 31)) << 7) + kg;
#pragma unroll
      for (int kk = 0; kk < 8; ++kk) {
        bf16x8 b = *(const bf16x8*)(wt + kk * 16);
        acc0 = __builtin_amdgcn_mfma_f32_32x32x16_bf16(hf[0][kk], b, acc0, 0, 0, 0);
        acc1 = __builtin_amdgcn_mfma_f32_32x32x16_bf16(hf[1][kk], b, acc1, 0, 0, 0);
      }
      int kout = nt * 32 + (lane & 31);
      float bo = (kout < 1000) ? b_o[kout] : 0.f;
#pragma unroll
      for (int reg = 0; reg < 16; ++reg) {
        int rr = (reg & 3) + 8 * (reg >> 2) + 4 * (lane >> 5);
        {
          float ov = (float)o_lds[rr * OLDW + kout];
          float rp = (ov == 0.f || ov == 1.f) ? 0.5f : 1.f;  // JAX clip tie-grad
          float on = ov - EPS * rp * (ov - bo - acc0[reg]);
          on = fminf(fmaxf(on, 0.f), 1.f);
          o_lds[rr * OLDW + kout] = (bf16_t)on;
        }
        {
          int r = rr + 32;
          float ov = (float)o_lds[r * OLDW + kout];
          float rp = (ov == 0.f || ov == 1.f) ? 0.5f : 1.f;
          float on = ov - EPS * rp * (ov - bo - acc1[reg]);
          on = fminf(fmaxf(on, 0.f), 1.f);
          o_lds[r * OLDW + kout] = (bf16_t)on;
        }
      }
    }
    __syncthreads();  // all h_t reads (hf preloads) done before h overwrite

    // ---- h-update from this wave's C tile
    {
      int j = nw * 32 + (lane & 31);
      float bh = b_h[j];
#pragma unroll
      for (int reg = 0; reg < 16; ++reg) {
        int r = mw * 32 + (reg & 3) + 8 * (reg >> 2) + 4 * (lane >> 5);
        float av = A[(size_t)(row0 + r) * 128 + j];
        float hv = (float)h_lds[r * HLDW + j];
        float rp = (hv == 0.f || hv == 1.f) ? 0.5f : 1.f;
        float hn = hv - EPS * rp * (hv - bh - av - accc[reg]);
        hn = fminf(fmaxf(hn, 0.f), 1.f);
        h_lds[r * HLDW + j] = (bf16_t)hn;
      }
    }
  }
  __syncthreads();

  // ---- epilogue: log_softmax per row over 1000 cols
  for (int r = w * 8; r < w * 8 + 8; ++r) {
    float m = -1e30f;
    for (int k = lane; k < 1000; k += 64) m = fmaxf(m, (float)o_lds[r * OLDW + k]);
#pragma unroll
    for (int s = 32; s > 0; s >>= 1) m = fmaxf(m, __shfl_xor(m, s));
    float sum = 0.f;
    for (int k = lane; k < 1000; k += 64) sum += expf((float)o_lds[r * OLDW + k] - m);
#pragma unroll
    for (int s = 32; s > 0; s >>= 1) sum += __shfl_xor(sum, s);
    float lse = m + logf(sum);
    for (int k = lane; k < 1000; k += 64)
      out[(size_t)(row0 + r) * 1000 + k] = (float)o_lds[r * OLDW + k] - lse;
  }
}

extern "C" void kernel_launch(void* const* d_in, const int* in_sizes, int n_in,
                              void* d_out, int out_size, void* d_ws, size_t ws_size,
                              hipStream_t stream) {
  const float* x   = (const float*)d_in[0];
  const float* h0  = (const float*)d_in[1];
  const float* o0  = (const float*)d_in[2];
  // d_in[3] = b_in: unused by the h/o gradients
  const float* b_h = (const float*)d_in[4];
  const float* b_o = (const float*)d_in[5];
  const float* W1  = (const float*)d_in[6];
  const float* W2  = (const float*)d_in[7];
  const int*   nit = (const int*)d_in[8];
  float* out = (float*)d_out;

  char* ws = (char*)d_ws;
  float*  A   = (float*)ws;                                  // 8192*128*4 = 4 MB
  bf16_t* W1t = (bf16_t*)(ws + 4194304);                     // 256 KB
  bf16_t* W2b = (bf16_t*)(ws + 4194304 + 262144);            // 256 KB
  bf16_t* W2t = (bf16_t*)(ws + 4194304 + 524288);            // 256 KB

  prep_weights<<<512, 256, 0, stream>>>(W1, W2, W1t, W2b, W2t);
  gemm_A<<<128, 256, 0, stream>>>(x, W1t, A);
  eqprop<<<128, 512, 0, stream>>>(h0, o0, b_h, b_o, A, W2b, W2t, nit, out);
}

// Round 2
// 888.455 us; speedup vs baseline: 1.1147x; 1.1147x over previous
//
#include <hip/hip_runtime.h>
#include <hip/hip_bf16.h>

typedef __bf16 bf16_t;
typedef __bf16 bf16x8 __attribute__((ext_vector_type(8)));
typedef float f32x16 __attribute__((ext_vector_type(16)));

#define EPS 0.5f

// XOR swizzle: spreads 8 consecutive rows across 8 distinct 16B LDS slots.
// o rows: 1024 bf16 = 2048 B stride; h rows: 128 bf16 = 256 B stride.
__device__ __forceinline__ int oswz(int row, int kbyte) {
  return (row << 11) + (kbyte ^ ((row & 7) << 4));
}
__device__ __forceinline__ int hswz(int row, int jbyte) {
  return (row << 8) + (jbyte ^ ((row & 7) << 4));
}

// ---------------- one-time weight conversion ----------------
// W1 [1024][128] f32 -> W1t [128][1024] bf16
// W2 [128][1000] f32 -> W2b [128][1024] bf16 (k-padded) and W2t [1024][128] bf16
__global__ __launch_bounds__(256) void prep_weights(
    const float* __restrict__ W1, const float* __restrict__ W2,
    bf16_t* __restrict__ W1t, bf16_t* __restrict__ W2b, bf16_t* __restrict__ W2t) {
  int idx = blockIdx.x * 256 + threadIdx.x;
  if (idx < 131072) {
    { int j = idx >> 10, i = idx & 1023; W1t[idx] = (bf16_t)W1[i * 128 + j]; }
    { int j = idx >> 10, k = idx & 1023;
      W2b[idx] = (bf16_t)((k < 1000) ? W2[j * 1000 + k] : 0.f); }
    { int k = idx >> 7, j = idx & 127;
      W2t[idx] = (bf16_t)((k < 1000) ? W2[j * 1000 + k] : 0.f); }
  }
}

// ---------------- A = x @ W1 (f32 out), bf16 MFMA ----------------
__global__ __launch_bounds__(256) void gemm_A(
    const float* __restrict__ x, const bf16_t* __restrict__ W1t,
    float* __restrict__ A) {
  int lane = threadIdx.x & 63, w = threadIdx.x >> 6;
  int row0 = blockIdx.x * 64;
  int mt = w & 1, np = (w >> 1) * 2;
  f32x16 acc0 = {}, acc1 = {};
  int ar = row0 + mt * 32 + (lane & 31);
  int kg = (lane >> 5) * 8;
  const float* xrow = x + (size_t)ar * 1024 + kg;
  const bf16_t* b0 = W1t + ((np * 32 + (lane & 31)) << 10) + kg;
  const bf16_t* b1 = W1t + (((np + 1) * 32 + (lane & 31)) << 10) + kg;
#pragma unroll 4
  for (int ks = 0; ks < 64; ++ks) {
    float xv[8];
    *(float4*)&xv[0] = *(const float4*)(xrow + ks * 16);
    *(float4*)&xv[4] = *(const float4*)(xrow + ks * 16 + 4);
    bf16x8 a;
#pragma unroll
    for (int i = 0; i < 8; ++i) a[i] = (bf16_t)xv[i];
    bf16x8 f0 = *(const bf16x8*)(b0 + ks * 16);
    bf16x8 f1 = *(const bf16x8*)(b1 + ks * 16);
    acc0 = __builtin_amdgcn_mfma_f32_32x32x16_bf16(a, f0, acc0, 0, 0, 0);
    acc1 = __builtin_amdgcn_mfma_f32_32x32x16_bf16(a, f1, acc1, 0, 0, 0);
  }
#pragma unroll
  for (int reg = 0; reg < 16; ++reg) {
    int r = mt * 32 + (reg & 3) + 8 * (reg >> 2) + 4 * (lane >> 5);
    A[(size_t)(row0 + r) * 128 + np * 32 + (lane & 31)] = acc0[reg];
    A[(size_t)(row0 + r) * 128 + (np + 1) * 32 + (lane & 31)] = acc1[reg];
  }
}

// ---------------- persistent relaxation + log_softmax ----------------
// grid 256 x 512 threads. BT=32 rows/block. 8 waves: C-pass wave (nw=w&3,
// kw=w>>2): n-tile nw, K-half kw, with the W2b slice RESIDENT in 128 VGPRs.
// D-pass: wave w owns n-tiles w*4..w*4+3, streams W2t from L2.
__global__ __launch_bounds__(512, 2) void eqprop(
    const float* __restrict__ h0, const float* __restrict__ o0,
    const float* __restrict__ b_h, const float* __restrict__ b_o,
    const float* __restrict__ A, const bf16_t* __restrict__ W2b,
    const bf16_t* __restrict__ W2t, const int* __restrict__ nit,
    float* __restrict__ out) {
  __shared__ bf16_t o_lds[32 * 1024];     // 64 KB, swizzled
  __shared__ bf16_t h_lds[32 * 128];      //  8 KB, swizzled
  __shared__ float c_red[4][32][32];      // 16 KB, C-pass K-reduction

  const int tid = threadIdx.x;
  const int lane = tid & 63, w = tid >> 6;
  const int lo = lane & 31, hi = lane >> 5;
  const int row0 = blockIdx.x * 32;
  const int nw = w & 3, kw = w >> 2;
  char* ob = (char*)o_lds;
  char* hb = (char*)h_lds;

  // ---- init LDS state from inputs
  for (int idx = tid; idx < 32 * 1024; idx += 512) {
    int r = idx >> 10, k = idx & 1023;
    float v = (k < 1000) ? o0[(size_t)(row0 + r) * 1000 + k] : 0.f;
    *(bf16_t*)(ob + oswz(r, k << 1)) = (bf16_t)v;
  }
  for (int idx = tid; idx < 32 * 128; idx += 512) {
    int r = idx >> 7, j = idx & 127;
    *(bf16_t*)(hb + hswz(r, j << 1)) = (bf16_t)h0[(size_t)(row0 + r) * 128 + j];
  }

  // ---- resident W2b fragments for this wave's C slice (128 VGPRs)
  bf16x8 wb[32];
#pragma unroll
  for (int ks = 0; ks < 32; ++ks)
    wb[ks] = *(const bf16x8*)(W2b + (size_t)(nw * 32 + lo) * 1024 +
                              kw * 512 + ks * 16 + hi * 8);

  const float bh = b_h[nw * 32 + lo];
  float bo[4];
#pragma unroll
  for (int i = 0; i < 4; ++i) {
    int kout = (w * 4 + i) * 32 + lo;
    bo[i] = (kout < 1000) ? b_o[kout] : 0.f;
  }
  const int T = nit[0];
  __syncthreads();

  for (int t = 0; t < T; ++t) {
    // ---- C-pass: partial C[b,j] over this wave's K-half (reg-resident B)
    f32x16 cacc = {};
#pragma unroll
    for (int ks = 0; ks < 32; ++ks) {
      bf16x8 a = *(const bf16x8*)(ob + oswz(lo, (kw * 512 + ks * 16 + hi * 8) << 1));
      cacc = __builtin_amdgcn_mfma_f32_32x32x16_bf16(a, wb[ks], cacc, 0, 0, 0);
    }
    // A-slice (x@W1) loads for the h-update (L2-resident, issued early)
    float av[16];
    if (kw == 0) {
#pragma unroll
      for (int reg = 0; reg < 16; ++reg) {
        int r = (reg & 3) + 8 * (reg >> 2) + 4 * hi;
        av[reg] = A[(size_t)(row0 + r) * 128 + nw * 32 + lo];
      }
    }
    // h_t fragments for the D-pass (must pre-load before h is overwritten)
    bf16x8 hf[8];
#pragma unroll
    for (int kk = 0; kk < 8; ++kk)
      hf[kk] = *(const bf16x8*)(hb + hswz(lo, (kk * 16 + hi * 8) << 1));
    // publish K-half partial
    if (kw == 1) {
#pragma unroll
      for (int reg = 0; reg < 16; ++reg) {
        int r = (reg & 3) + 8 * (reg >> 2) + 4 * hi;
        c_red[nw][r][lo] = cacc[reg];
      }
    }
    __syncthreads();  // o reads + hf preloads done; partials visible

    // ---- h-update (kw==0 waves): h_new = clip(h - eps*rho'*(h - bh - A - C))
    if (kw == 0) {
#pragma unroll
      for (int reg = 0; reg < 16; ++reg) {
        int r = (reg & 3) + 8 * (reg >> 2) + 4 * hi;
        float c = cacc[reg] + c_red[nw][r][lo];
        bf16_t* hp = (bf16_t*)(hb + hswz(r, (nw * 32 + lo) << 1));
        float hv = (float)*hp;
        float rp = (hv == 0.f || hv == 1.f) ? 0.5f : 1.f;  // JAX clip tie-grad
        float hn = hv - EPS * rp * (hv - bh - av[reg] - c);
        *hp = (bf16_t)fminf(fmaxf(hn, 0.f), 1.f);
      }
    }

    // ---- D-pass: 4 n-tiles/wave, W2t streamed from L2; o updated in place
#pragma unroll
    for (int i = 0; i < 4; ++i) {
      int nt = w * 4 + i;
      f32x16 dacc = {};
      const bf16_t* wt = W2t + (size_t)(nt * 32 + lo) * 128 + hi * 8;
#pragma unroll
      for (int kk = 0; kk < 8; ++kk) {
        bf16x8 b = *(const bf16x8*)(wt + kk * 16);
        dacc = __builtin_amdgcn_mfma_f32_32x32x16_bf16(hf[kk], b, dacc, 0, 0, 0);
      }
      int kout = nt * 32 + lo;
#pragma unroll
      for (int reg = 0; reg < 16; ++reg) {
        int r = (reg & 3) + 8 * (reg >> 2) + 4 * hi;
        bf16_t* op = (bf16_t*)(ob + oswz(r, kout << 1));
        float ov = (float)*op;
        float rp = (ov == 0.f || ov == 1.f) ? 0.5f : 1.f;
        float on = ov - EPS * rp * (ov - bo[i] - dacc[reg]);
        *op = (bf16_t)fminf(fmaxf(on, 0.f), 1.f);
      }
    }
    __syncthreads();  // iteration complete: o/h writes visible to next C-pass
  }

  // ---- epilogue: log_softmax per row over 1000 cols (4 rows per wave)
  for (int r = w * 4; r < w * 4 + 4; ++r) {
    float m = -1e30f;
    for (int k = lane; k < 1000; k += 64)
      m = fmaxf(m, (float)*(const bf16_t*)(ob + oswz(r, k << 1)));
#pragma unroll
    for (int s = 32; s > 0; s >>= 1) m = fmaxf(m, __shfl_xor(m, s));
    float sum = 0.f;
    for (int k = lane; k < 1000; k += 64)
      sum += expf((float)*(const bf16_t*)(ob + oswz(r, k << 1)) - m);
#pragma unroll
    for (int s = 32; s > 0; s >>= 1) sum += __shfl_xor(sum, s);
    float lse = m + logf(sum);
    for (int k = lane; k < 1000; k += 64)
      out[(size_t)(row0 + r) * 1000 + k] =
          (float)*(const bf16_t*)(ob + oswz(r, k << 1)) - lse;
  }
}

extern "C" void kernel_launch(void* const* d_in, const int* in_sizes, int n_in,
                              void* d_out, int out_size, void* d_ws, size_t ws_size,
                              hipStream_t stream) {
  const float* x   = (const float*)d_in[0];
  const float* h0  = (const float*)d_in[1];
  const float* o0  = (const float*)d_in[2];
  // d_in[3] = b_in: unused by the h/o gradients
  const float* b_h = (const float*)d_in[4];
  const float* b_o = (const float*)d_in[5];
  const float* W1  = (const float*)d_in[6];
  const float* W2  = (const float*)d_in[7];
  const int*   nit = (const int*)d_in[8];
  float* out = (float*)d_out;

  char* ws = (char*)d_ws;
  float*  A   = (float*)ws;                           // 8192*128*4 = 4 MB
  bf16_t* W1t = (bf16_t*)(ws + 4194304);              // 256 KB
  bf16_t* W2b = (bf16_t*)(ws + 4194304 + 262144);     // 256 KB
  bf16_t* W2t = (bf16_t*)(ws + 4194304 + 524288);     // 256 KB

  prep_weights<<<512, 256, 0, stream>>>(W1, W2, W1t, W2b, W2t);
  gemm_A<<<128, 256, 0, stream>>>(x, W1t, A);
  eqprop<<<256, 512, 0, stream>>>(h0, o0, b_h, b_o, A, W2b, W2t, nit, out);
}

// Round 3
// 546.568 us; speedup vs baseline: 1.8120x; 1.6255x over previous
//
#include <hip/hip_runtime.h>
#include <hip/hip_bf16.h>

typedef __bf16 bf16_t;
typedef __bf16 bf16x4_t __attribute__((ext_vector_type(4)));
typedef __bf16 bf16x8 __attribute__((ext_vector_type(8)));
typedef float f32x4 __attribute__((ext_vector_type(4)));
typedef float f32x16 __attribute__((ext_vector_type(16)));

#define EPS 0.5f

// 16-slot XOR swizzle (conflict-free column reads across rows).
// o rows: 1024 bf16 = 2048 B stride; h rows: 128 bf16 = 256 B stride.
__device__ __forceinline__ int oswz(int row, int kbyte) {
  return (row << 11) + (kbyte ^ ((row & 15) << 4));
}
__device__ __forceinline__ int hswz(int row, int jbyte) {
  return (row << 8) + (jbyte ^ ((row & 15) << 4));
}

// ---------------- one-time weight conversion ----------------
// W1 [1024][128] f32 -> W1t [128][1024] bf16
// W2 [128][1000] f32 -> W2b [128][1024] bf16 (k-padded) and W2t [1024][128] bf16
__global__ __launch_bounds__(256) void prep_weights(
    const float* __restrict__ W1, const float* __restrict__ W2,
    bf16_t* __restrict__ W1t, bf16_t* __restrict__ W2b, bf16_t* __restrict__ W2t) {
  int idx = blockIdx.x * 256 + threadIdx.x;
  if (idx < 131072) {
    { int j = idx >> 10, i = idx & 1023; W1t[idx] = (bf16_t)W1[i * 128 + j]; }
    { int j = idx >> 10, k = idx & 1023;
      W2b[idx] = (bf16_t)((k < 1000) ? W2[j * 1000 + k] : 0.f); }
    { int k = idx >> 7, j = idx & 127;
      W2t[idx] = (bf16_t)((k < 1000) ? W2[j * 1000 + k] : 0.f); }
  }
}

// ---------------- A = x @ W1 (f32 out), bf16 MFMA (verified r1/r2) --------
__global__ __launch_bounds__(256) void gemm_A(
    const float* __restrict__ x, const bf16_t* __restrict__ W1t,
    float* __restrict__ A) {
  int lane = threadIdx.x & 63, w = threadIdx.x >> 6;
  int row0 = blockIdx.x * 64;
  int mt = w & 1, np = (w >> 1) * 2;
  f32x16 acc0 = {}, acc1 = {};
  int ar = row0 + mt * 32 + (lane & 31);
  int kg = (lane >> 5) * 8;
  const float* xrow = x + (size_t)ar * 1024 + kg;
  const bf16_t* b0 = W1t + ((np * 32 + (lane & 31)) << 10) + kg;
  const bf16_t* b1 = W1t + (((np + 1) * 32 + (lane & 31)) << 10) + kg;
#pragma unroll 4
  for (int ks = 0; ks < 64; ++ks) {
    float xv[8];
    *(float4*)&xv[0] = *(const float4*)(xrow + ks * 16);
    *(float4*)&xv[4] = *(const float4*)(xrow + ks * 16 + 4);
    bf16x8 a;
#pragma unroll
    for (int i = 0; i < 8; ++i) a[i] = (bf16_t)xv[i];
    bf16x8 f0 = *(const bf16x8*)(b0 + ks * 16);
    bf16x8 f1 = *(const bf16x8*)(b1 + ks * 16);
    acc0 = __builtin_amdgcn_mfma_f32_32x32x16_bf16(a, f0, acc0, 0, 0, 0);
    acc1 = __builtin_amdgcn_mfma_f32_32x32x16_bf16(a, f1, acc1, 0, 0, 0);
  }
#pragma unroll
  for (int reg = 0; reg < 16; ++reg) {
    int r = mt * 32 + (reg & 3) + 8 * (reg >> 2) + 4 * (lane >> 5);
    A[(size_t)(row0 + r) * 128 + np * 32 + (lane & 31)] = acc0[reg];
    A[(size_t)(row0 + r) * 128 + (np + 1) * 32 + (lane & 31)] = acc1[reg];
  }
}

// o-update for one D-tile: lane owns 4 consecutive kouts per reg-group.
__device__ __forceinline__ void o_update(const f32x16& d, int kbase,
                                         const char* op, char* on,
                                         const float* bo_lds, int lo) {
#pragma unroll
  for (int q = 0; q < 4; ++q) {
    int kout = kbase + 8 * q;
    float4 bo4 = *(const float4*)(bo_lds + kout);
    bf16x4_t oo = *(const bf16x4_t*)(op + oswz(lo, kout * 2));
    bf16x4_t onv;
#pragma unroll
    for (int r = 0; r < 4; ++r) {
      float ov = (float)oo[r];
      float dv = d[q * 4 + r];
      float bov = r == 0 ? bo4.x : r == 1 ? bo4.y : r == 2 ? bo4.z : bo4.w;
      float rp = (ov == 0.f || ov == 1.f) ? 0.5f : 1.f;  // JAX clip tie-grad
      float nv = ov - EPS * rp * (ov - bov - dv);
      onv[r] = (bf16_t)fminf(fmaxf(nv, 0.f), 1.f);
    }
    *(bf16x4_t*)(on + oswz(lo, kout * 2)) = onv;
  }
}

// ---------------- persistent relaxation + log_softmax ----------------
// 256 blocks x 1024 threads (16 waves, 1 block/CU). Double-buffered state.
// Waves 0-7 (C-group): Ct = W2b . o^T via 16x16x32, W2b slice in 128 VGPRs;
//   then h-update (vectorized b64 RMW). Waves 8-15 (D-group): Dt = W2t . h^T
//   via 32x32x16, W2t slice in 128 VGPRs; then o-update. 1 barrier/iter.
__global__ __launch_bounds__(1024, 4) void eqprop(
    const float* __restrict__ h0, const float* __restrict__ o0,
    const float* __restrict__ b_h, const float* __restrict__ b_o,
    const float* __restrict__ A, const bf16_t* __restrict__ W2b,
    const bf16_t* __restrict__ W2t, const int* __restrict__ nit,
    float* __restrict__ out) {
  __shared__ __align__(16) char ob[2][65536];   // o state, swizzled bf16
  __shared__ __align__(16) char hb[2][8192];    // h state, swizzled bf16
  __shared__ float bo_lds[1024];                // b_o (f32, broadcast reads)

  const int tid = threadIdx.x, lane = tid & 63, w = tid >> 6;
  const int lo = lane & 31, hi = lane >> 5;
  const int l4 = lane & 15, g4 = (lane >> 4) & 3;
  const int row0 = blockIdx.x * 32;

  // ---- init state buffers [0] and b_o table
  for (int idx = tid; idx < 32 * 1024; idx += 1024) {
    int r = idx >> 10, k = idx & 1023;
    float v = (k < 1000) ? o0[(size_t)(row0 + r) * 1000 + k] : 0.f;
    *(bf16_t*)(&ob[0][0] + oswz(r, k * 2)) = (bf16_t)v;
  }
  for (int idx = tid; idx < 32 * 128; idx += 1024) {
    int r = idx >> 7, j = idx & 127;
    *(bf16_t*)(&hb[0][0] + hswz(r, j * 2)) = (bf16_t)h0[(size_t)(row0 + r) * 128 + j];
  }
  bo_lds[tid] = (tid < 1000) ? b_o[tid] : 0.f;

  const int T = nit[0];
  int p = 0;

  if (w < 8) {
    // ================= C-group: j-tile w (16 j), both 16-row b-tiles ======
    bf16x8 wb[32];  // W2b[j0..j0+15][:] A-frags, K=1024 (128 VGPR)
#pragma unroll
    for (int ks = 0; ks < 32; ++ks)
      wb[ks] = *(const bf16x8*)(W2b + (size_t)(w * 16 + l4) * 1024 + ks * 32 + g4 * 8);
    const int j0 = w * 16 + g4 * 4;
    const float4 bh4 = *(const float4*)(b_h + j0);
    __syncthreads();
    for (int t = 0; t < T; ++t) {
      const char* op = &ob[p][0];
      f32x4 ca = {}, cb = {};
#pragma unroll
      for (int ks = 0; ks < 32; ++ks) {
        bf16x8 f0 = *(const bf16x8*)(op + oswz(l4, ks * 64 + g4 * 16));
        bf16x8 f1 = *(const bf16x8*)(op + oswz(16 + l4, ks * 64 + g4 * 16));
        ca = __builtin_amdgcn_mfma_f32_16x16x32_bf16(wb[ks], f0, ca, 0, 0, 0);
        cb = __builtin_amdgcn_mfma_f32_16x16x32_bf16(wb[ks], f1, cb, 0, 0, 0);
      }
      // h-update: lane owns (b = bt*16+l4, j = j0..j0+3)
#pragma unroll
      for (int bt = 0; bt < 2; ++bt) {
        int b = bt * 16 + l4;
        float4 a4 = *(const float4*)(A + (size_t)(row0 + b) * 128 + j0);
        bf16x4_t ho = *(const bf16x4_t*)(&hb[p][0] + hswz(b, j0 * 2));
        bf16x4_t hn;
#pragma unroll
        for (int r = 0; r < 4; ++r) {
          float hv = (float)ho[r];
          float c = bt ? cb[r] : ca[r];
          float av = r == 0 ? a4.x : r == 1 ? a4.y : r == 2 ? a4.z : a4.w;
          float bhv = r == 0 ? bh4.x : r == 1 ? bh4.y : r == 2 ? bh4.z : bh4.w;
          float rp = (hv == 0.f || hv == 1.f) ? 0.5f : 1.f;
          float nv = hv - EPS * rp * (hv - bhv - av - c);
          hn[r] = (bf16_t)fminf(fmaxf(nv, 0.f), 1.f);
        }
        *(bf16x4_t*)(&hb[p ^ 1][0] + hswz(b, j0 * 2)) = hn;
      }
      __syncthreads();
      p ^= 1;
    }
  } else {
    // ================= D-group: kout-tiles 4i..4i+3 (32-wide) ============
    const int iw = w - 8;
    bf16x8 wt[4][8];  // W2t A-frags, resident (128 VGPR)
#pragma unroll
    for (int t4 = 0; t4 < 4; ++t4)
#pragma unroll
      for (int kk = 0; kk < 8; ++kk)
        wt[t4][kk] = *(const bf16x8*)(W2t +
            (size_t)((iw * 4 + t4) * 32 + lo) * 128 + kk * 16 + hi * 8);
    __syncthreads();
    for (int t = 0; t < T; ++t) {
      const char* hp = &hb[p][0];
      bf16x8 hf[8];  // h B-frags (shared across 4 tiles)
#pragma unroll
      for (int kk = 0; kk < 8; ++kk)
        hf[kk] = *(const bf16x8*)(hp + hswz(lo, kk * 32 + hi * 16));
      f32x16 d0 = {}, d1 = {}, d2 = {}, d3 = {};
#pragma unroll
      for (int kk = 0; kk < 8; ++kk) {
        d0 = __builtin_amdgcn_mfma_f32_32x32x16_bf16(wt[0][kk], hf[kk], d0, 0, 0, 0);
        d1 = __builtin_amdgcn_mfma_f32_32x32x16_bf16(wt[1][kk], hf[kk], d1, 0, 0, 0);
        d2 = __builtin_amdgcn_mfma_f32_32x32x16_bf16(wt[2][kk], hf[kk], d2, 0, 0, 0);
        d3 = __builtin_amdgcn_mfma_f32_32x32x16_bf16(wt[3][kk], hf[kk], d3, 0, 0, 0);
      }
      const char* op = &ob[p][0];
      char* on = &ob[p ^ 1][0];
      o_update(d0, (iw * 4 + 0) * 32 + 4 * hi, op, on, bo_lds, lo);
      o_update(d1, (iw * 4 + 1) * 32 + 4 * hi, op, on, bo_lds, lo);
      o_update(d2, (iw * 4 + 2) * 32 + 4 * hi, op, on, bo_lds, lo);
      o_update(d3, (iw * 4 + 3) * 32 + 4 * hi, op, on, bo_lds, lo);
      __syncthreads();
      p ^= 1;
    }
  }
  __syncthreads();

  // ---- epilogue: log_softmax per row (2 rows per wave), coalesced out
  const char* of = &ob[p][0];
  for (int r = w * 2; r < w * 2 + 2; ++r) {
    float m = -1e30f;
    for (int k = lane; k < 1000; k += 64)
      m = fmaxf(m, (float)*(const bf16_t*)(of + oswz(r, k * 2)));
#pragma unroll
    for (int s = 32; s > 0; s >>= 1) m = fmaxf(m, __shfl_xor(m, s));
    float sum = 0.f;
    for (int k = lane; k < 1000; k += 64)
      sum += expf((float)*(const bf16_t*)(of + oswz(r, k * 2)) - m);
#pragma unroll
    for (int s = 32; s > 0; s >>= 1) sum += __shfl_xor(sum, s);
    float lse = m + logf(sum);
    for (int k = lane; k < 1000; k += 64)
      out[(size_t)(row0 + r) * 1000 + k] =
          (float)*(const bf16_t*)(of + oswz(r, k * 2)) - lse;
  }
}

extern "C" void kernel_launch(void* const* d_in, const int* in_sizes, int n_in,
                              void* d_out, int out_size, void* d_ws, size_t ws_size,
                              hipStream_t stream) {
  const float* x   = (const float*)d_in[0];
  const float* h0  = (const float*)d_in[1];
  const float* o0  = (const float*)d_in[2];
  // d_in[3] = b_in: unused by the h/o gradients
  const float* b_h = (const float*)d_in[4];
  const float* b_o = (const float*)d_in[5];
  const float* W1  = (const float*)d_in[6];
  const float* W2  = (const float*)d_in[7];
  const int*   nit = (const int*)d_in[8];
  float* out = (float*)d_out;

  char* ws = (char*)d_ws;
  float*  A   = (float*)ws;                           // 8192*128*4 = 4 MB
  bf16_t* W1t = (bf16_t*)(ws + 4194304);              // 256 KB
  bf16_t* W2b = (bf16_t*)(ws + 4194304 + 262144);     // 256 KB
  bf16_t* W2t = (bf16_t*)(ws + 4194304 + 524288);     // 256 KB

  prep_weights<<<512, 256, 0, stream>>>(W1, W2, W1t, W2b, W2t);
  gemm_A<<<128, 256, 0, stream>>>(x, W1t, A);
  eqprop<<<256, 1024, 0, stream>>>(h0, o0, b_h, b_o, A, W2b, W2t, nit, out);
}

// Round 4
// 226.999 us; speedup vs baseline: 4.3629x; 2.4078x over previous
//
#include <hip/hip_runtime.h>
#include <hip/hip_bf16.h>

typedef __bf16 bf16_t;
typedef __bf16 bf16x4_t __attribute__((ext_vector_type(4)));
typedef __bf16 bf16x8 __attribute__((ext_vector_type(8)));
typedef float f32x16 __attribute__((ext_vector_type(16)));

#define EPS 0.5f
#define MFMA32(a, b, c) __builtin_amdgcn_mfma_f32_32x32x16_bf16(a, b, c, 0, 0, 0)

// 16-slot XOR swizzle. o rows: 1024 bf16 = 2048 B; h rows: 128 bf16 = 256 B.
__device__ __forceinline__ int oswz(int row, int kbyte) {
  return (row << 11) + (kbyte ^ ((row & 15) << 4));
}
__device__ __forceinline__ int hswz(int row, int jbyte) {
  return (row << 8) + (jbyte ^ ((row & 15) << 4));
}

// ---------------- one-time weight conversion ----------------
// W1t [128 j][1024 i] bf16 (for gemm_A).
// W2B: fragment-major for C-pass: idx = ((jt*64+s)*64+lane)*8+e,
//      element = W2[jt*32+(lane&31)][s*16+(lane>>5)*8+e]  (0 if k>=1000)
// W2T: fragment-major for D-pass: idx = ((kt*8+js)*64+lane)*8+e,
//      element = W2[js*16+(lane>>5)*8+e][kt*32+(lane&31)]  (0 if k>=1000)
__global__ __launch_bounds__(256) void prep_weights(
    const float* __restrict__ W1, const float* __restrict__ W2,
    bf16_t* __restrict__ W1t, bf16_t* __restrict__ W2B, bf16_t* __restrict__ W2T) {
  int idx = blockIdx.x * 256 + threadIdx.x;
  if (idx < 131072) {
    { int j = idx >> 10, i = idx & 1023; W1t[idx] = (bf16_t)W1[i * 128 + j]; }
    { int e = idx & 7, l = (idx >> 3) & 63, s = (idx >> 9) & 63, jt = idx >> 15;
      int j = jt * 32 + (l & 31), k = s * 16 + (l >> 5) * 8 + e;
      W2B[idx] = (bf16_t)((k < 1000) ? W2[j * 1000 + k] : 0.f); }
    { int e = idx & 7, l = (idx >> 3) & 63, js = (idx >> 9) & 7, kt = idx >> 12;
      int k = kt * 32 + (l & 31), j = js * 16 + (l >> 5) * 8 + e;
      W2T[idx] = (bf16_t)((k < 1000) ? W2[j * 1000 + k] : 0.f); }
  }
}

// ---------------- A = x @ W1 (f32 out), bf16 MFMA (verified r1-r3) --------
__global__ __launch_bounds__(256) void gemm_A(
    const float* __restrict__ x, const bf16_t* __restrict__ W1t,
    float* __restrict__ A) {
  int lane = threadIdx.x & 63, w = threadIdx.x >> 6;
  int row0 = blockIdx.x * 64;
  int mt = w & 1, np = (w >> 1) * 2;
  f32x16 acc0 = {}, acc1 = {};
  int ar = row0 + mt * 32 + (lane & 31);
  int kg = (lane >> 5) * 8;
  const float* xrow = x + (size_t)ar * 1024 + kg;
  const bf16_t* b0 = W1t + ((np * 32 + (lane & 31)) << 10) + kg;
  const bf16_t* b1 = W1t + (((np + 1) * 32 + (lane & 31)) << 10) + kg;
#pragma unroll 4
  for (int ks = 0; ks < 64; ++ks) {
    float xv[8];
    *(float4*)&xv[0] = *(const float4*)(xrow + ks * 16);
    *(float4*)&xv[4] = *(const float4*)(xrow + ks * 16 + 4);
    bf16x8 a;
#pragma unroll
    for (int i = 0; i < 8; ++i) a[i] = (bf16_t)xv[i];
    bf16x8 f0 = *(const bf16x8*)(b0 + ks * 16);
    bf16x8 f1 = *(const bf16x8*)(b1 + ks * 16);
    acc0 = MFMA32(a, f0, acc0);
    acc1 = MFMA32(a, f1, acc1);
  }
#pragma unroll
  for (int reg = 0; reg < 16; ++reg) {
    int r = mt * 32 + (reg & 3) + 8 * (reg >> 2) + 4 * (lane >> 5);
    A[(size_t)(row0 + r) * 128 + np * 32 + (lane & 31)] = acc0[reg];
    A[(size_t)(row0 + r) * 128 + (np + 1) * 32 + (lane & 31)] = acc1[reg];
  }
}

// ---------------- persistent relaxation + log_softmax ----------------
// 256 blocks x 1024 threads (16 waves, 1 block/CU, <=128 regs/wave).
// Waves 0-3 (C): Ct[32j,32b], jt=w, full k=1024; 16 frags resident, 48
//   streamed from L2 (frag-major, coalesced). Then h-update (own tile, no
//   cross-wave reduce). Waves 4-15 (D): Dt[k-slice,32b]; 12 frags resident.
// o/h double-buffered in LDS -> ONE barrier per iteration.
__global__ __launch_bounds__(1024, 4) void eqprop(
    const float* __restrict__ h0, const float* __restrict__ o0,
    const float* __restrict__ b_h, const float* __restrict__ b_o,
    const float* __restrict__ A, const bf16_t* __restrict__ W2B,
    const bf16_t* __restrict__ W2T, const int* __restrict__ nit,
    float* __restrict__ out) {
  __shared__ __align__(16) char ob[2][65536];   // o state, swizzled bf16
  __shared__ __align__(16) char hb[2][8192];    // h state, swizzled bf16
  __shared__ float bo_lds[1024];

  const int tid = threadIdx.x, lane = tid & 63, w = tid >> 6;
  const int lo = lane & 31, hi = lane >> 5;
  const int row0 = blockIdx.x * 32;

  // ---- init state buffers [0] (vectorized) and b_o table
  for (int idx = tid; idx < 8192; idx += 1024) {   // 32 rows x 256 k-quads
    int r = idx >> 8, k4 = (idx & 255) * 4;
    bf16x4_t v4 = {};
    if (k4 < 1000) {
      float4 v = *(const float4*)(o0 + (size_t)(row0 + r) * 1000 + k4);
      v4[0] = (bf16_t)v.x; v4[1] = (bf16_t)v.y; v4[2] = (bf16_t)v.z; v4[3] = (bf16_t)v.w;
    }
    *(bf16x4_t*)(&ob[0][0] + oswz(r, k4 * 2)) = v4;
  }
  {
    int idx = tid;                                  // 32 rows x 32 j-quads
    if (idx < 1024) {
      int r = idx >> 5, j4 = (idx & 31) * 4;
      float4 v = *(const float4*)(h0 + (size_t)(row0 + r) * 128 + j4);
      bf16x4_t v4;
      v4[0] = (bf16_t)v.x; v4[1] = (bf16_t)v.y; v4[2] = (bf16_t)v.z; v4[3] = (bf16_t)v.w;
      *(bf16x4_t*)(&hb[0][0] + hswz(r, j4 * 2)) = v4;
    }
  }
  bo_lds[tid] = (tid < 1000) ? b_o[tid] : 0.f;

  const int T = nit[0];
  int p = 0;
  __syncthreads();

  if (w < 4) {
    // ================= C-waves: Ct[j,b] = sum_k W2[j,k] o[b,k] ============
    const int jt = w;
    const bf16_t* WB = W2B + (size_t)jt * 64 * 512 + lane * 8;
    bf16x8 wres[16];
#pragma unroll
    for (int s = 0; s < 16; ++s) wres[s] = *(const bf16x8*)(WB + s * 512);
    const bf16_t* WS = WB + 16 * 512;

    for (int t = 0; t < T; ++t) {
      const char* op = &ob[p][0];
      f32x16 acc = {};
#pragma unroll
      for (int s = 0; s < 16; ++s) {
        bf16x8 of = *(const bf16x8*)(op + oswz(lo, s * 32 + hi * 16));
        acc = MFMA32(wres[s], of, acc);
      }
#pragma unroll 1
      for (int c = 0; c < 12; ++c) {
        bf16x8 w0 = *(const bf16x8*)(WS + (c * 4 + 0) * 512);
        bf16x8 w1 = *(const bf16x8*)(WS + (c * 4 + 1) * 512);
        bf16x8 w2 = *(const bf16x8*)(WS + (c * 4 + 2) * 512);
        bf16x8 w3 = *(const bf16x8*)(WS + (c * 4 + 3) * 512);
        int s0 = (16 + c * 4) * 32 + hi * 16;
        bf16x8 f0 = *(const bf16x8*)(op + oswz(lo, s0));
        bf16x8 f1 = *(const bf16x8*)(op + oswz(lo, s0 + 32));
        bf16x8 f2 = *(const bf16x8*)(op + oswz(lo, s0 + 64));
        bf16x8 f3 = *(const bf16x8*)(op + oswz(lo, s0 + 96));
        acc = MFMA32(w0, f0, acc);
        acc = MFMA32(w1, f1, acc);
        acc = MFMA32(w2, f2, acc);
        acc = MFMA32(w3, f3, acc);
      }
      // ---- h-update: lane owns b=lo, j = jt*32 + q*8 + 4*hi + r
      const char* hp = &hb[p][0];
      char* hn = &hb[p ^ 1][0];
#pragma unroll
      for (int q = 0; q < 4; ++q) {
        int jb = jt * 32 + q * 8 + 4 * hi;
        float av[4], bh[4];
        *(float4*)av = *(const float4*)(A + (size_t)(row0 + lo) * 128 + jb);
        *(float4*)bh = *(const float4*)(b_h + jb);
        bf16x4_t hv4 = *(const bf16x4_t*)(hp + hswz(lo, jb * 2));
        bf16x4_t hn4;
#pragma unroll
        for (int r = 0; r < 4; ++r) {
          float hv = (float)hv4[r];
          float rp = (hv == 0.f || hv == 1.f) ? 0.5f : 1.f;  // JAX clip tie-grad
          float nv = hv - EPS * rp * (hv - bh[r] - av[r] - acc[q * 4 + r]);
          hn4[r] = (bf16_t)fminf(fmaxf(nv, 0.f), 1.f);
        }
        *(bf16x4_t*)(hn + hswz(lo, jb * 2)) = hn4;
      }
      __syncthreads();
      p ^= 1;
    }
  } else {
    // ================= D-waves: Dt[k,b] = sum_j W2[j,k] h[b,j] ============
    const int wd = w - 4;
    const int kt0 = (wd < 8) ? wd * 3 : 24 + (wd - 8) * 2;
    const int nkt = (wd < 8) ? 3 : 2;
    const bf16_t* WT = W2T + (size_t)kt0 * 8 * 512 + lane * 8;
    bf16x8 wres[12];   // ktile0 frags 0-7, ktile1 frags 8-11
#pragma unroll
    for (int f = 0; f < 12; ++f) wres[f] = *(const bf16x8*)(WT + f * 512);

    for (int t = 0; t < T; ++t) {
      const char* hp = &hb[p][0];
      const char* op = &ob[p][0];
      char* on = &ob[p ^ 1][0];

#pragma unroll 1
      for (int kl = 0; kl < nkt; ++kl) {
        f32x16 acc = {};
        if (kl == 0) {
#pragma unroll
          for (int js = 0; js < 8; ++js) {
            bf16x8 hf = *(const bf16x8*)(hp + hswz(lo, js * 32 + hi * 16));
            acc = MFMA32(wres[js], hf, acc);
          }
        } else if (kl == 1) {
          bf16x8 s0 = *(const bf16x8*)(WT + 12 * 512);
          bf16x8 s1 = *(const bf16x8*)(WT + 13 * 512);
          bf16x8 s2 = *(const bf16x8*)(WT + 14 * 512);
          bf16x8 s3 = *(const bf16x8*)(WT + 15 * 512);
#pragma unroll
          for (int js = 0; js < 4; ++js) {
            bf16x8 hf = *(const bf16x8*)(hp + hswz(lo, js * 32 + hi * 16));
            acc = MFMA32(wres[8 + js], hf, acc);
          }
          {
            bf16x8 h4 = *(const bf16x8*)(hp + hswz(lo, 4 * 32 + hi * 16));
            bf16x8 h5 = *(const bf16x8*)(hp + hswz(lo, 5 * 32 + hi * 16));
            bf16x8 h6 = *(const bf16x8*)(hp + hswz(lo, 6 * 32 + hi * 16));
            bf16x8 h7 = *(const bf16x8*)(hp + hswz(lo, 7 * 32 + hi * 16));
            acc = MFMA32(s0, h4, acc);
            acc = MFMA32(s1, h5, acc);
            acc = MFMA32(s2, h6, acc);
            acc = MFMA32(s3, h7, acc);
          }
        } else {
          const bf16_t* WK = WT + 16 * 512;
          bf16x8 s0 = *(const bf16x8*)(WK + 0 * 512);
          bf16x8 s1 = *(const bf16x8*)(WK + 1 * 512);
          bf16x8 s2 = *(const bf16x8*)(WK + 2 * 512);
          bf16x8 s3 = *(const bf16x8*)(WK + 3 * 512);
#pragma unroll
          for (int js = 0; js < 4; ++js) {
            bf16x8 hf = *(const bf16x8*)(hp + hswz(lo, js * 32 + hi * 16));
            acc = MFMA32((js == 0) ? s0 : (js == 1) ? s1 : (js == 2) ? s2 : s3,
                         hf, acc);
          }
          bf16x8 s4 = *(const bf16x8*)(WK + 4 * 512);
          bf16x8 s5 = *(const bf16x8*)(WK + 5 * 512);
          bf16x8 s6 = *(const bf16x8*)(WK + 6 * 512);
          bf16x8 s7 = *(const bf16x8*)(WK + 7 * 512);
#pragma unroll
          for (int js = 4; js < 8; ++js) {
            bf16x8 hf = *(const bf16x8*)(hp + hswz(lo, js * 32 + hi * 16));
            acc = MFMA32((js == 4) ? s4 : (js == 5) ? s5 : (js == 6) ? s6 : s7,
                         hf, acc);
          }
        }
        // ---- o-update: lane owns b=lo, k = kt*32 + q*8 + 4*hi + r
        int kt = kt0 + kl;
#pragma unroll
        for (int q = 0; q < 4; ++q) {
          int kb = kt * 32 + q * 8 + 4 * hi;
          float bo[4];
          *(float4*)bo = *(const float4*)(bo_lds + kb);
          bf16x4_t ov4 = *(const bf16x4_t*)(op + oswz(lo, kb * 2));
          bf16x4_t on4;
#pragma unroll
          for (int r = 0; r < 4; ++r) {
            float ov = (float)ov4[r];
            float rp = (ov == 0.f || ov == 1.f) ? 0.5f : 1.f;
            float nv = ov - EPS * rp * (ov - bo[r] - acc[q * 4 + r]);
            on4[r] = (bf16_t)fminf(fmaxf(nv, 0.f), 1.f);
          }
          *(bf16x4_t*)(on + oswz(lo, kb * 2)) = on4;
        }
      }
      __syncthreads();
      p ^= 1;
    }
  }
  __syncthreads();

  // ---- epilogue: log_softmax per row (2 rows per wave)
  const char* of = &ob[p][0];
  for (int r = w * 2; r < w * 2 + 2; ++r) {
    float m = -1e30f;
    for (int k = lane; k < 1000; k += 64)
      m = fmaxf(m, (float)*(const bf16_t*)(of + oswz(r, k * 2)));
#pragma unroll
    for (int s = 32; s > 0; s >>= 1) m = fmaxf(m, __shfl_xor(m, s));
    float sum = 0.f;
    for (int k = lane; k < 1000; k += 64)
      sum += expf((float)*(const bf16_t*)(of + oswz(r, k * 2)) - m);
#pragma unroll
    for (int s = 32; s > 0; s >>= 1) sum += __shfl_xor(sum, s);
    float lse = m + logf(sum);
    for (int k = lane; k < 1000; k += 64)
      out[(size_t)(row0 + r) * 1000 + k] =
          (float)*(const bf16_t*)(of + oswz(r, k * 2)) - lse;
  }
}

extern "C" void kernel_launch(void* const* d_in, const int* in_sizes, int n_in,
                              void* d_out, int out_size, void* d_ws, size_t ws_size,
                              hipStream_t stream) {
  const float* x   = (const float*)d_in[0];
  const float* h0  = (const float*)d_in[1];
  const float* o0  = (const float*)d_in[2];
  // d_in[3] = b_in: unused by the h/o gradients
  const float* b_h = (const float*)d_in[4];
  const float* b_o = (const float*)d_in[5];
  const float* W1  = (const float*)d_in[6];
  const float* W2  = (const float*)d_in[7];
  const int*   nit = (const int*)d_in[8];
  float* out = (float*)d_out;

  char* ws = (char*)d_ws;
  float*  A   = (float*)ws;                           // 8192*128*4 = 4 MB
  bf16_t* W1t = (bf16_t*)(ws + 4194304);              // 256 KB
  bf16_t* W2B = (bf16_t*)(ws + 4194304 + 262144);     // 256 KB
  bf16_t* W2T = (bf16_t*)(ws + 4194304 + 524288);     // 256 KB

  prep_weights<<<512, 256, 0, stream>>>(W1, W2, W1t, W2B, W2T);
  gemm_A<<<128, 256, 0, stream>>>(x, W1t, A);
  eqprop<<<256, 1024, 0, stream>>>(h0, o0, b_h, b_o, A, W2B, W2T, nit, out);
}